// Round 5
// baseline (272.618 us; speedup 1.0000x reference)
//
#include <hip/hip_runtime.h>
#include <math.h>

#define BB 8
#define TT 48
#define DD 512
#define NN 1024

// ---------- z = [x ; tgt_next] @ E : 4x4 register tile per thread (round-3 exact) ----------
__global__ __launch_bounds__(256) void k_gemm_z(const float* __restrict__ x,
                                                const float* __restrict__ tg,
                                                const float* __restrict__ E,
                                                float* __restrict__ z_x,
                                                float* __restrict__ z_t) {
    int rt = blockIdx.x, ct = blockIdx.y;
    int tid = threadIdx.x;
    int c16 = tid & 15, r4 = tid >> 4;
    int row0 = rt * 32 + r4 * 4;
    int col0 = ct * 64 + c16 * 4;

    const float* rp[4];
#pragma unroll
    for (int i = 0; i < 4; i++) {
        int gr = row0 + i;
        if (gr < BB * TT) {
            rp[i] = x + (size_t)gr * DD;
        } else {
            int bt = gr - BB * TT;
            int s = bt + 1;
            if (s > BB * TT - 1) s = BB * TT - 1;  // t=47 rows: garbage, masked by k_ln
            rp[i] = tg + (size_t)s * DD;
        }
    }
    const float* eb = E + col0;

    float acc[4][4];
#pragma unroll
    for (int i = 0; i < 4; i++)
#pragma unroll
        for (int j = 0; j < 4; j++) acc[i][j] = 0.f;

    for (int d0 = 0; d0 < DD; d0 += 4) {
        float a[4][4], e[4][4];
#pragma unroll
        for (int i = 0; i < 4; i++) {
            float4 v = *reinterpret_cast<const float4*>(rp[i] + d0);
            a[i][0] = v.x; a[i][1] = v.y; a[i][2] = v.z; a[i][3] = v.w;
        }
#pragma unroll
        for (int k = 0; k < 4; k++) {
            float4 v = *reinterpret_cast<const float4*>(eb + (size_t)(d0 + k) * NN);
            e[k][0] = v.x; e[k][1] = v.y; e[k][2] = v.z; e[k][3] = v.w;
        }
#pragma unroll
        for (int i = 0; i < 4; i++)
#pragma unroll
            for (int k = 0; k < 4; k++)
#pragma unroll
                for (int j = 0; j < 4; j++)
                    acc[i][j] = fmaf(a[i][k], e[k][j], acc[i][j]);
    }

#pragma unroll
    for (int i = 0; i < 4; i++) {
        int gr = row0 + i;
        float4 v = make_float4(acc[i][0], acc[i][1], acc[i][2], acc[i][3]);
        if (gr < BB * TT)
            *reinterpret_cast<float4*>(z_x + (size_t)gr * NN + col0) = v;
        else
            *reinterpret_cast<float4*>(z_t + (size_t)(gr - BB * TT) * NN + col0) = v;
    }
}

// ---------- LN + relu (round-3 exact) ----------
__global__ __launch_bounds__(256) void k_ln(const float* __restrict__ z_x,
                                            const float* __restrict__ z_t,
                                            float* __restrict__ xn,
                                            float* __restrict__ tn) {
    int bt = blockIdx.x;
    int t = bt % TT;
    int tid = threadIdx.x;
    __shared__ float rs_[256], rq_[256];

    const float* src = z_x + (size_t)bt * NN;
    float v0 = src[tid], v1 = src[tid + 256], v2 = src[tid + 512], v3 = src[tid + 768];
    rs_[tid] = v0 + v1 + v2 + v3;
    rq_[tid] = v0 * v0 + v1 * v1 + v2 * v2 + v3 * v3;
    __syncthreads();
    for (int off = 128; off > 0; off >>= 1) {
        if (tid < off) { rs_[tid] += rs_[tid + off]; rq_[tid] += rq_[tid + off]; }
        __syncthreads();
    }
    float mu = rs_[0] * (1.f / NN);
    float var = rq_[0] * (1.f / NN) - mu * mu;
    float rstd = rsqrtf(var + 1e-5f);
    float* xrow = xn + (size_t)bt * NN;
    xrow[tid]       = fmaxf((v0 - mu) * rstd, 0.f);
    xrow[tid + 256] = fmaxf((v1 - mu) * rstd, 0.f);
    xrow[tid + 512] = fmaxf((v2 - mu) * rstd, 0.f);
    xrow[tid + 768] = fmaxf((v3 - mu) * rstd, 0.f);
    __syncthreads();

    float* trow = tn + (size_t)bt * NN;
    if (t < TT - 1) {
        const float* s2 = z_t + (size_t)bt * NN;
        float u0 = s2[tid], u1 = s2[tid + 256], u2 = s2[tid + 512], u3 = s2[tid + 768];
        rs_[tid] = u0 + u1 + u2 + u3;
        rq_[tid] = u0 * u0 + u1 * u1 + u2 * u2 + u3 * u3;
        __syncthreads();
        for (int off = 128; off > 0; off >>= 1) {
            if (tid < off) { rs_[tid] += rs_[tid + off]; rq_[tid] += rq_[tid + off]; }
            __syncthreads();
        }
        float mu2 = rs_[0] * (1.f / NN);
        float var2 = rq_[0] * (1.f / NN) - mu2 * mu2;
        float r2 = rsqrtf(var2 + 1e-5f);
        trow[tid]       = fmaxf((u0 - mu2) * r2, 0.f);
        trow[tid + 256] = fmaxf((u1 - mu2) * r2, 0.f);
        trow[tid + 512] = fmaxf((u2 - mu2) * r2, 0.f);
        trow[tid + 768] = fmaxf((u3 - mu2) * r2, 0.f);
    } else {
        trow[tid] = 0.f; trow[tid + 256] = 0.f; trow[tid + 512] = 0.f; trow[tid + 768] = 0.f;
    }
}

// ---------- the recurrence, G truly in registers ----------
// 1024 blocks: bid = state<<9 | b<<6 | nc<<2 | ccg.
// 4 waves per block; wave wid handles col chunk cc = ccg*4+wid (64 cols), rows nc*64..+63.
// Per thread: g[64] scalar floats = 64 VGPRs. No LDS, no cross-wave traffic.
// r_part layout identical to round 3: chunk = (state*8+b)*16+nc.
__global__ __launch_bounds__(256, 2) void k_sweep(const float* __restrict__ xn,
                                                  const float* __restrict__ tn,
                                                  float* __restrict__ r_part) {
    int bid = blockIdx.x;
    int ccg = bid & 3, nc = (bid >> 2) & 15, b = (bid >> 6) & 7, state = bid >> 9;
    int tid = threadIdx.x;
    int lane = tid & 63;
    int wid = __builtin_amdgcn_readfirstlane(tid >> 6);
    int cc = ccg * 4 + wid;
    int n0 = nc * 64;
    int col = cc * 64 + lane;

    float g[64];
#pragma unroll
    for (int n = 0; n < 64; n++)
        g[n] = (state == 0 && nc == cc && n == lane) ? 0.5f : 0.f;

    const float* wb  = xn + (size_t)b * TT * NN + n0;              // wave-uniform rows
    const float* mvb = (state ? tn : xn) + (size_t)b * TT * NN + col;
    float* rp = r_part + ((size_t)((state * 8 + b) * 16 + nc) * TT) * NN + col;

#pragma unroll 1
    for (int t = 0; t < TT; t++) {
        const float* xrow = wb + (size_t)t * NN;
        float mv = mvb[(size_t)t * NN];
        float sc = (t < TT - 1) ? 0.5f : 0.0f;   // folds do_upd into the operand
        float mh = mv * sc;
        float a0 = 0.f, a1 = 0.f, a2 = 0.f, a3 = 0.f;
#pragma unroll
        for (int n = 0; n < 64; n += 4) {
            float w0 = xrow[n], w1 = xrow[n + 1], w2 = xrow[n + 2], w3 = xrow[n + 3];
            if (w0 > 0.f) { a0 = fmaf(w0, g[n],     a0); g[n]     = fmaxf(g[n],     w0 * mh); }
            if (w1 > 0.f) { a1 = fmaf(w1, g[n + 1], a1); g[n + 1] = fmaxf(g[n + 1], w1 * mh); }
            if (w2 > 0.f) { a2 = fmaf(w2, g[n + 2], a2); g[n + 2] = fmaxf(g[n + 2], w2 * mh); }
            if (w3 > 0.f) { a3 = fmaf(w3, g[n + 3], a3); g[n + 3] = fmaxf(g[n + 3], w3 * mh); }
        }
        rp[(size_t)t * NN] = (a0 + a1) + (a2 + a3);
    }
}

// ---------- reduce partials over nc, mix, @Dy, relu (round-3 exact) ----------
__global__ __launch_bounds__(256) void k_y(const float* __restrict__ r_part,
                                           const float* __restrict__ Dy,
                                           const float* __restrict__ mixp,
                                           float* __restrict__ out) {
    int bb = blockIdx.x;
    int tg = bb & 15, b = bb >> 4;
    int tid = threadIdx.x;
    __shared__ float mixs[3][NN];
    float alpha = 1.f / (1.f + expf(-mixp[0]));

#pragma unroll
    for (int tt = 0; tt < 3; tt++) {
        int t = tg * 3 + tt;
        float spx = 0.f, spy = 0.f, spz = 0.f, spw = 0.f;
        float stx = 0.f, sty = 0.f, stz = 0.f, stw = 0.f;
#pragma unroll
        for (int nc = 0; nc < 16; nc++) {
            int bidp = (b * 16 + nc);
            int bidt = ((8 + b) * 16 + nc);
            float4 p = *reinterpret_cast<const float4*>(r_part + ((size_t)bidp * TT + t) * NN + tid * 4);
            float4 q = *reinterpret_cast<const float4*>(r_part + ((size_t)bidt * TT + t) * NN + tid * 4);
            spx += p.x; spy += p.y; spz += p.z; spw += p.w;
            stx += q.x; sty += q.y; stz += q.z; stw += q.w;
        }
        float4 m4;
        m4.x = alpha * spx + (1.f - alpha) * stx;
        m4.y = alpha * spy + (1.f - alpha) * sty;
        m4.z = alpha * spz + (1.f - alpha) * stz;
        m4.w = alpha * spw + (1.f - alpha) * stw;
        *reinterpret_cast<float4*>(&mixs[tt][tid * 4]) = m4;
    }
    __syncthreads();

    float acc[3][2];
#pragma unroll
    for (int tt = 0; tt < 3; tt++) { acc[tt][0] = 0.f; acc[tt][1] = 0.f; }

    for (int m = 0; m < NN; m += 4) {
        float w[3][4];
#pragma unroll
        for (int tt = 0; tt < 3; tt++) {
            float4 v = *reinterpret_cast<const float4*>(&mixs[tt][m]);
            w[tt][0] = v.x; w[tt][1] = v.y; w[tt][2] = v.z; w[tt][3] = v.w;
        }
#pragma unroll
        for (int j = 0; j < 4; j++) {
            float d0 = Dy[(size_t)(m + j) * DD + tid];
            float d1 = Dy[(size_t)(m + j) * DD + tid + 256];
#pragma unroll
            for (int tt = 0; tt < 3; tt++) {
                acc[tt][0] = fmaf(w[tt][j], d0, acc[tt][0]);
                acc[tt][1] = fmaf(w[tt][j], d1, acc[tt][1]);
            }
        }
    }
#pragma unroll
    for (int tt = 0; tt < 3; tt++) {
        int t = tg * 3 + tt;
        out[((size_t)b * TT + t) * DD + tid]       = fmaxf(acc[tt][0], 0.f);
        out[((size_t)b * TT + t) * DD + tid + 256] = fmaxf(acc[tt][1], 0.f);
    }
}

extern "C" void kernel_launch(void* const* d_in, const int* in_sizes, int n_in,
                              void* d_out, int out_size, void* d_ws, size_t ws_size,
                              hipStream_t stream) {
    const float* x    = (const float*)d_in[0];   // [8,48,512]
    const float* tg   = (const float*)d_in[1];   // [8,48,512]
    const float* E    = (const float*)d_in[2];   // [512,1024]
    const float* Dy   = (const float*)d_in[3];   // [1024,512]
    const float* mixp = (const float*)d_in[4];   // scalar
    float* out = (float*)d_out;                  // [8,48,512]

    float* ws = (float*)d_ws;
    float* z_x    = ws;                               // 384*1024
    float* z_t    = z_x + (size_t)384 * 1024;
    float* xn     = z_t + (size_t)384 * 1024;
    float* tn     = xn + (size_t)384 * 1024;
    float* r_part = tn + (size_t)384 * 1024;          // 256 chunks * 48 * 1024 floats

    k_gemm_z<<<dim3(24, 16), 256, 0, stream>>>(x, tg, E, z_x, z_t);
    k_ln<<<384, 256, 0, stream>>>(z_x, z_t, xn, tn);
    k_sweep<<<1024, 256, 0, stream>>>(xn, tn, r_part);
    k_y<<<128, 256, 0, stream>>>(r_part, Dy, mixp, out);
}

// Round 6
// 268.406 us; speedup vs baseline: 1.0157x; 1.0157x over previous
//
#include <hip/hip_runtime.h>
#include <math.h>

#define BB 8
#define TT 48
#define DD 512
#define NN 1024

// ---------- z = [x ; tgt_next] @ E ----------
// 384 blocks: block br -> rows {2br, 2br+1}, all 1024 cols. Thread: 4 cols x 2 rows.
// Per-output K-chain is d=0..511 ascending fmaf -> bitwise identical to prior rounds.
__global__ __launch_bounds__(256) void k_gemm_z(const float* __restrict__ x,
                                                const float* __restrict__ tg,
                                                const float* __restrict__ E,
                                                float* __restrict__ z_x,
                                                float* __restrict__ z_t) {
    int br = blockIdx.x;
    int tid = threadIdx.x;
    int col0 = tid * 4;

    const float* row[2];
#pragma unroll
    for (int i = 0; i < 2; i++) {
        int gr = br * 2 + i;
        if (gr < BB * TT) {
            row[i] = x + (size_t)gr * DD;
        } else {
            int bt = gr - BB * TT;
            int s = bt + 1;
            if (s > BB * TT - 1) s = BB * TT - 1;  // t=47 rows: garbage, masked by k_ln
            row[i] = tg + (size_t)s * DD;
        }
    }

    float4 acc0 = make_float4(0.f, 0.f, 0.f, 0.f);
    float4 acc1 = make_float4(0.f, 0.f, 0.f, 0.f);
    for (int d = 0; d < DD; d++) {
        float4 e = *reinterpret_cast<const float4*>(E + (size_t)d * NN + col0);
        float a0 = row[0][d];   // block-uniform address -> s_load
        float a1 = row[1][d];
        acc0.x = fmaf(a0, e.x, acc0.x);
        acc0.y = fmaf(a0, e.y, acc0.y);
        acc0.z = fmaf(a0, e.z, acc0.z);
        acc0.w = fmaf(a0, e.w, acc0.w);
        acc1.x = fmaf(a1, e.x, acc1.x);
        acc1.y = fmaf(a1, e.y, acc1.y);
        acc1.z = fmaf(a1, e.z, acc1.z);
        acc1.w = fmaf(a1, e.w, acc1.w);
    }

#pragma unroll
    for (int i = 0; i < 2; i++) {
        int gr = br * 2 + i;
        float4 v = (i == 0) ? acc0 : acc1;
        if (gr < BB * TT)
            *reinterpret_cast<float4*>(z_x + (size_t)gr * NN + col0) = v;
        else
            *reinterpret_cast<float4*>(z_t + (size_t)(gr - BB * TT) * NN + col0) = v;
    }
}

// ---------- LN + relu (round-3 exact) ----------
__global__ __launch_bounds__(256) void k_ln(const float* __restrict__ z_x,
                                            const float* __restrict__ z_t,
                                            float* __restrict__ xn,
                                            float* __restrict__ tn) {
    int bt = blockIdx.x;
    int t = bt % TT;
    int tid = threadIdx.x;
    __shared__ float rs_[256], rq_[256];

    const float* src = z_x + (size_t)bt * NN;
    float v0 = src[tid], v1 = src[tid + 256], v2 = src[tid + 512], v3 = src[tid + 768];
    rs_[tid] = v0 + v1 + v2 + v3;
    rq_[tid] = v0 * v0 + v1 * v1 + v2 * v2 + v3 * v3;
    __syncthreads();
    for (int off = 128; off > 0; off >>= 1) {
        if (tid < off) { rs_[tid] += rs_[tid + off]; rq_[tid] += rq_[tid + off]; }
        __syncthreads();
    }
    float mu = rs_[0] * (1.f / NN);
    float var = rq_[0] * (1.f / NN) - mu * mu;
    float rstd = rsqrtf(var + 1e-5f);
    float* xrow = xn + (size_t)bt * NN;
    xrow[tid]       = fmaxf((v0 - mu) * rstd, 0.f);
    xrow[tid + 256] = fmaxf((v1 - mu) * rstd, 0.f);
    xrow[tid + 512] = fmaxf((v2 - mu) * rstd, 0.f);
    xrow[tid + 768] = fmaxf((v3 - mu) * rstd, 0.f);
    __syncthreads();

    float* trow = tn + (size_t)bt * NN;
    if (t < TT - 1) {
        const float* s2 = z_t + (size_t)bt * NN;
        float u0 = s2[tid], u1 = s2[tid + 256], u2 = s2[tid + 512], u3 = s2[tid + 768];
        rs_[tid] = u0 + u1 + u2 + u3;
        rq_[tid] = u0 * u0 + u1 * u1 + u2 * u2 + u3 * u3;
        __syncthreads();
        for (int off = 128; off > 0; off >>= 1) {
            if (tid < off) { rs_[tid] += rs_[tid + off]; rq_[tid] += rq_[tid + off]; }
            __syncthreads();
        }
        float mu2 = rs_[0] * (1.f / NN);
        float var2 = rq_[0] * (1.f / NN) - mu2 * mu2;
        float r2 = rsqrtf(var2 + 1e-5f);
        trow[tid]       = fmaxf((u0 - mu2) * r2, 0.f);
        trow[tid + 256] = fmaxf((u1 - mu2) * r2, 0.f);
        trow[tid + 512] = fmaxf((u2 - mu2) * r2, 0.f);
        trow[tid + 768] = fmaxf((u3 - mu2) * r2, 0.f);
    } else {
        trow[tid] = 0.f; trow[tid + 256] = 0.f; trow[tid + 512] = 0.f; trow[tid + 768] = 0.f;
    }
}

// ---------- the recurrence: G in 64 NAMED scalar registers ----------
// 1024 blocks: bid = state<<9 | b<<6 | nc<<2 | ccg. Wave wid -> col chunk cc=ccg*4+wid.
// Named g0..g63 guarantee SROA (every access compile-time constant).
// Weights: one lane-resident VGPR per t, readlane -> SGPR -> scalar branch + SGPR fma operand.

#define GI(n) float g##n = (state == 0 && nc == cc && (n) == lane) ? 0.5f : 0.f;
#define REP64(X) X(0) X(1) X(2) X(3) X(4) X(5) X(6) X(7) X(8) X(9) X(10) X(11) X(12) X(13) \
    X(14) X(15) X(16) X(17) X(18) X(19) X(20) X(21) X(22) X(23) X(24) X(25) X(26) X(27) \
    X(28) X(29) X(30) X(31) X(32) X(33) X(34) X(35) X(36) X(37) X(38) X(39) X(40) X(41) \
    X(42) X(43) X(44) X(45) X(46) X(47) X(48) X(49) X(50) X(51) X(52) X(53) X(54) X(55) \
    X(56) X(57) X(58) X(59) X(60) X(61) X(62) X(63)

#define GS(n, A) { float wn = __int_as_float(__builtin_amdgcn_readlane(__float_as_int(wv), (n))); \
                   if (wn > 0.f) { A = fmaf(wn, g##n, A); g##n = fmaxf(g##n, wn * mh); } }

__global__ __launch_bounds__(256, 2) void k_sweep(const float* __restrict__ xn,
                                                  const float* __restrict__ tn,
                                                  float* __restrict__ r_part) {
    int bid = blockIdx.x;
    int ccg = bid & 3, nc = (bid >> 2) & 15, b = (bid >> 6) & 7, state = bid >> 9;
    int tid = threadIdx.x;
    int lane = tid & 63;
    int wid = __builtin_amdgcn_readfirstlane(tid >> 6);
    int cc = ccg * 4 + wid;
    int n0 = nc * 64;
    int col = cc * 64 + lane;

    REP64(GI)

    const float* wb  = xn + (size_t)b * TT * NN + n0;              // weights, rows n0..n0+63
    const float* mvb = (state ? tn : xn) + (size_t)b * TT * NN + col;
    float* rp = r_part + ((size_t)((state * 8 + b) * 16 + nc) * TT) * NN + col;

#pragma unroll 1
    for (int t = 0; t < TT; t++) {
        float wv = wb[(size_t)t * NN + lane];   // 64 weights live across the wave's lanes
        float mv = mvb[(size_t)t * NN];
        float sc = (t < TT - 1) ? 0.5f : 0.0f;  // folds do_upd into the operand
        float mh = mv * sc;
        float a0 = 0.f, a1 = 0.f, a2 = 0.f, a3 = 0.f;
        GS(0,a0)  GS(1,a1)  GS(2,a2)  GS(3,a3)
        GS(4,a0)  GS(5,a1)  GS(6,a2)  GS(7,a3)
        GS(8,a0)  GS(9,a1)  GS(10,a2) GS(11,a3)
        GS(12,a0) GS(13,a1) GS(14,a2) GS(15,a3)
        GS(16,a0) GS(17,a1) GS(18,a2) GS(19,a3)
        GS(20,a0) GS(21,a1) GS(22,a2) GS(23,a3)
        GS(24,a0) GS(25,a1) GS(26,a2) GS(27,a3)
        GS(28,a0) GS(29,a1) GS(30,a2) GS(31,a3)
        GS(32,a0) GS(33,a1) GS(34,a2) GS(35,a3)
        GS(36,a0) GS(37,a1) GS(38,a2) GS(39,a3)
        GS(40,a0) GS(41,a1) GS(42,a2) GS(43,a3)
        GS(44,a0) GS(45,a1) GS(46,a2) GS(47,a3)
        GS(48,a0) GS(49,a1) GS(50,a2) GS(51,a3)
        GS(52,a0) GS(53,a1) GS(54,a2) GS(55,a3)
        GS(56,a0) GS(57,a1) GS(58,a2) GS(59,a3)
        GS(60,a0) GS(61,a1) GS(62,a2) GS(63,a3)
        rp[(size_t)t * NN] = (a0 + a1) + (a2 + a3);
    }
}

// ---------- reduce partials over nc, mix, @Dy, relu (round-3 exact) ----------
__global__ __launch_bounds__(256) void k_y(const float* __restrict__ r_part,
                                           const float* __restrict__ Dy,
                                           const float* __restrict__ mixp,
                                           float* __restrict__ out) {
    int bb = blockIdx.x;
    int tg = bb & 15, b = bb >> 4;
    int tid = threadIdx.x;
    __shared__ float mixs[3][NN];
    float alpha = 1.f / (1.f + expf(-mixp[0]));

#pragma unroll
    for (int tt = 0; tt < 3; tt++) {
        int t = tg * 3 + tt;
        float spx = 0.f, spy = 0.f, spz = 0.f, spw = 0.f;
        float stx = 0.f, sty = 0.f, stz = 0.f, stw = 0.f;
#pragma unroll
        for (int nc = 0; nc < 16; nc++) {
            int bidp = (b * 16 + nc);
            int bidt = ((8 + b) * 16 + nc);
            float4 p = *reinterpret_cast<const float4*>(r_part + ((size_t)bidp * TT + t) * NN + tid * 4);
            float4 q = *reinterpret_cast<const float4*>(r_part + ((size_t)bidt * TT + t) * NN + tid * 4);
            spx += p.x; spy += p.y; spz += p.z; spw += p.w;
            stx += q.x; sty += q.y; stz += q.z; stw += q.w;
        }
        float4 m4;
        m4.x = alpha * spx + (1.f - alpha) * stx;
        m4.y = alpha * spy + (1.f - alpha) * sty;
        m4.z = alpha * spz + (1.f - alpha) * stz;
        m4.w = alpha * spw + (1.f - alpha) * stw;
        *reinterpret_cast<float4*>(&mixs[tt][tid * 4]) = m4;
    }
    __syncthreads();

    float acc[3][2];
#pragma unroll
    for (int tt = 0; tt < 3; tt++) { acc[tt][0] = 0.f; acc[tt][1] = 0.f; }

    for (int m = 0; m < NN; m += 4) {
        float w[3][4];
#pragma unroll
        for (int tt = 0; tt < 3; tt++) {
            float4 v = *reinterpret_cast<const float4*>(&mixs[tt][m]);
            w[tt][0] = v.x; w[tt][1] = v.y; w[tt][2] = v.z; w[tt][3] = v.w;
        }
#pragma unroll
        for (int j = 0; j < 4; j++) {
            float d0 = Dy[(size_t)(m + j) * DD + tid];
            float d1 = Dy[(size_t)(m + j) * DD + tid + 256];
#pragma unroll
            for (int tt = 0; tt < 3; tt++) {
                acc[tt][0] = fmaf(w[tt][j], d0, acc[tt][0]);
                acc[tt][1] = fmaf(w[tt][j], d1, acc[tt][1]);
            }
        }
    }
#pragma unroll
    for (int tt = 0; tt < 3; tt++) {
        int t = tg * 3 + tt;
        out[((size_t)b * TT + t) * DD + tid]       = fmaxf(acc[tt][0], 0.f);
        out[((size_t)b * TT + t) * DD + tid + 256] = fmaxf(acc[tt][1], 0.f);
    }
}

extern "C" void kernel_launch(void* const* d_in, const int* in_sizes, int n_in,
                              void* d_out, int out_size, void* d_ws, size_t ws_size,
                              hipStream_t stream) {
    const float* x    = (const float*)d_in[0];   // [8,48,512]
    const float* tg   = (const float*)d_in[1];   // [8,48,512]
    const float* E    = (const float*)d_in[2];   // [512,1024]
    const float* Dy   = (const float*)d_in[3];   // [1024,512]
    const float* mixp = (const float*)d_in[4];   // scalar
    float* out = (float*)d_out;                  // [8,48,512]

    float* ws = (float*)d_ws;
    float* z_x    = ws;                               // 384*1024
    float* z_t    = z_x + (size_t)384 * 1024;
    float* xn     = z_t + (size_t)384 * 1024;
    float* tn     = xn + (size_t)384 * 1024;
    float* r_part = tn + (size_t)384 * 1024;          // 256 chunks * 48 * 1024 floats

    k_gemm_z<<<384, 256, 0, stream>>>(x, tg, E, z_x, z_t);
    k_ln<<<384, 256, 0, stream>>>(z_x, z_t, xn, tn);
    k_sweep<<<1024, 256, 0, stream>>>(xn, tn, r_part);
    k_y<<<128, 256, 0, stream>>>(r_part, Dy, mixp, out);
}

// Round 7
// 193.614 us; speedup vs baseline: 1.4080x; 1.3863x over previous
//
#include <hip/hip_runtime.h>
#include <math.h>

#define BB 8
#define TT 48
#define DD 512
#define NN 1024

// ---------- z = [x ; tgt_next] @ E (round-6 exact) ----------
__global__ __launch_bounds__(256) void k_gemm_z(const float* __restrict__ x,
                                                const float* __restrict__ tg,
                                                const float* __restrict__ E,
                                                float* __restrict__ z_x,
                                                float* __restrict__ z_t) {
    int br = blockIdx.x;
    int tid = threadIdx.x;
    int col0 = tid * 4;

    const float* row[2];
#pragma unroll
    for (int i = 0; i < 2; i++) {
        int gr = br * 2 + i;
        if (gr < BB * TT) {
            row[i] = x + (size_t)gr * DD;
        } else {
            int bt = gr - BB * TT;
            int s = bt + 1;
            if (s > BB * TT - 1) s = BB * TT - 1;  // t=47 rows: garbage, masked by k_ln
            row[i] = tg + (size_t)s * DD;
        }
    }

    float4 acc0 = make_float4(0.f, 0.f, 0.f, 0.f);
    float4 acc1 = make_float4(0.f, 0.f, 0.f, 0.f);
    for (int d = 0; d < DD; d++) {
        float4 e = *reinterpret_cast<const float4*>(E + (size_t)d * NN + col0);
        float a0 = row[0][d];   // block-uniform address -> s_load
        float a1 = row[1][d];
        acc0.x = fmaf(a0, e.x, acc0.x);
        acc0.y = fmaf(a0, e.y, acc0.y);
        acc0.z = fmaf(a0, e.z, acc0.z);
        acc0.w = fmaf(a0, e.w, acc0.w);
        acc1.x = fmaf(a1, e.x, acc1.x);
        acc1.y = fmaf(a1, e.y, acc1.y);
        acc1.z = fmaf(a1, e.z, acc1.z);
        acc1.w = fmaf(a1, e.w, acc1.w);
    }

#pragma unroll
    for (int i = 0; i < 2; i++) {
        int gr = br * 2 + i;
        float4 v = (i == 0) ? acc0 : acc1;
        if (gr < BB * TT)
            *reinterpret_cast<float4*>(z_x + (size_t)gr * NN + col0) = v;
        else
            *reinterpret_cast<float4*>(z_t + (size_t)(gr - BB * TT) * NN + col0) = v;
    }
}

// ---------- LN + relu (round-3 exact) ----------
__global__ __launch_bounds__(256) void k_ln(const float* __restrict__ z_x,
                                            const float* __restrict__ z_t,
                                            float* __restrict__ xn,
                                            float* __restrict__ tn) {
    int bt = blockIdx.x;
    int t = bt % TT;
    int tid = threadIdx.x;
    __shared__ float rs_[256], rq_[256];

    const float* src = z_x + (size_t)bt * NN;
    float v0 = src[tid], v1 = src[tid + 256], v2 = src[tid + 512], v3 = src[tid + 768];
    rs_[tid] = v0 + v1 + v2 + v3;
    rq_[tid] = v0 * v0 + v1 * v1 + v2 * v2 + v3 * v3;
    __syncthreads();
    for (int off = 128; off > 0; off >>= 1) {
        if (tid < off) { rs_[tid] += rs_[tid + off]; rq_[tid] += rq_[tid + off]; }
        __syncthreads();
    }
    float mu = rs_[0] * (1.f / NN);
    float var = rq_[0] * (1.f / NN) - mu * mu;
    float rstd = rsqrtf(var + 1e-5f);
    float* xrow = xn + (size_t)bt * NN;
    xrow[tid]       = fmaxf((v0 - mu) * rstd, 0.f);
    xrow[tid + 256] = fmaxf((v1 - mu) * rstd, 0.f);
    xrow[tid + 512] = fmaxf((v2 - mu) * rstd, 0.f);
    xrow[tid + 768] = fmaxf((v3 - mu) * rstd, 0.f);
    __syncthreads();

    float* trow = tn + (size_t)bt * NN;
    if (t < TT - 1) {
        const float* s2 = z_t + (size_t)bt * NN;
        float u0 = s2[tid], u1 = s2[tid + 256], u2 = s2[tid + 512], u3 = s2[tid + 768];
        rs_[tid] = u0 + u1 + u2 + u3;
        rq_[tid] = u0 * u0 + u1 * u1 + u2 * u2 + u3 * u3;
        __syncthreads();
        for (int off = 128; off > 0; off >>= 1) {
            if (tid < off) { rs_[tid] += rs_[tid + off]; rq_[tid] += rq_[tid + off]; }
            __syncthreads();
        }
        float mu2 = rs_[0] * (1.f / NN);
        float var2 = rq_[0] * (1.f / NN) - mu2 * mu2;
        float r2 = rsqrtf(var2 + 1e-5f);
        trow[tid]       = fmaxf((u0 - mu2) * r2, 0.f);
        trow[tid + 256] = fmaxf((u1 - mu2) * r2, 0.f);
        trow[tid + 512] = fmaxf((u2 - mu2) * r2, 0.f);
        trow[tid + 768] = fmaxf((u3 - mu2) * r2, 0.f);
    } else {
        trow[tid] = 0.f; trow[tid + 256] = 0.f; trow[tid + 512] = 0.f; trow[tid + 768] = 0.f;
    }
}

// ---------- the recurrence: G in 64 NAMED registers, BRANCHLESS ----------
// 1024 blocks: bid = state<<9 | b<<6 | nc<<2 | ccg. Wave wid -> col chunk cc=ccg*4+wid.
// xn >= 0 and g >= 0 always, so the wn==0 case is a bit-exact no-op without a branch:
//   a = fmaf(0,g,a) == a ; g = fmaxf(g, 0*mh) == g.
// Straight-line body (no CFG) lets the allocator keep g0..g63 in VGPRs.
// Weights from wave-uniform addresses -> s_load (SGPR operand in the FMA).

#define GI(n) float g##n = (state == 0 && nc == cc && (n) == lane) ? 0.5f : 0.f;
#define REP64(X) X(0) X(1) X(2) X(3) X(4) X(5) X(6) X(7) X(8) X(9) X(10) X(11) X(12) X(13) \
    X(14) X(15) X(16) X(17) X(18) X(19) X(20) X(21) X(22) X(23) X(24) X(25) X(26) X(27) \
    X(28) X(29) X(30) X(31) X(32) X(33) X(34) X(35) X(36) X(37) X(38) X(39) X(40) X(41) \
    X(42) X(43) X(44) X(45) X(46) X(47) X(48) X(49) X(50) X(51) X(52) X(53) X(54) X(55) \
    X(56) X(57) X(58) X(59) X(60) X(61) X(62) X(63)

#define GS(n, A) { float wn = xrow[n]; A = fmaf(wn, g##n, A); g##n = fmaxf(g##n, wn * mh); }

__global__ __launch_bounds__(256, 2) void k_sweep(const float* __restrict__ xn,
                                                  const float* __restrict__ tn,
                                                  float* __restrict__ r_part) {
    int bid = blockIdx.x;
    int ccg = bid & 3, nc = (bid >> 2) & 15, b = (bid >> 6) & 7, state = bid >> 9;
    int tid = threadIdx.x;
    int lane = tid & 63;
    int wid = __builtin_amdgcn_readfirstlane(tid >> 6);
    int cc = ccg * 4 + wid;
    int n0 = nc * 64;
    int col = cc * 64 + lane;

    REP64(GI)

    const float* wb  = xn + (size_t)b * TT * NN + n0;              // wave-uniform rows
    const float* mvb = (state ? tn : xn) + (size_t)b * TT * NN + col;
    float* rp = r_part + ((size_t)((state * 8 + b) * 16 + nc) * TT) * NN + col;

#pragma unroll 1
    for (int t = 0; t < TT; t++) {
        const float* xrow = wb + (size_t)t * NN;   // uniform -> s_load chunks
        float mv = mvb[(size_t)t * NN];
        float sc = (t < TT - 1) ? 0.5f : 0.0f;     // folds do_upd into the operand
        float mh = mv * sc;
        float a0 = 0.f, a1 = 0.f, a2 = 0.f, a3 = 0.f;
        GS(0,a0)  GS(1,a1)  GS(2,a2)  GS(3,a3)
        GS(4,a0)  GS(5,a1)  GS(6,a2)  GS(7,a3)
        GS(8,a0)  GS(9,a1)  GS(10,a2) GS(11,a3)
        GS(12,a0) GS(13,a1) GS(14,a2) GS(15,a3)
        GS(16,a0) GS(17,a1) GS(18,a2) GS(19,a3)
        GS(20,a0) GS(21,a1) GS(22,a2) GS(23,a3)
        GS(24,a0) GS(25,a1) GS(26,a2) GS(27,a3)
        GS(28,a0) GS(29,a1) GS(30,a2) GS(31,a3)
        GS(32,a0) GS(33,a1) GS(34,a2) GS(35,a3)
        GS(36,a0) GS(37,a1) GS(38,a2) GS(39,a3)
        GS(40,a0) GS(41,a1) GS(42,a2) GS(43,a3)
        GS(44,a0) GS(45,a1) GS(46,a2) GS(47,a3)
        GS(48,a0) GS(49,a1) GS(50,a2) GS(51,a3)
        GS(52,a0) GS(53,a1) GS(54,a2) GS(55,a3)
        GS(56,a0) GS(57,a1) GS(58,a2) GS(59,a3)
        GS(60,a0) GS(61,a1) GS(62,a2) GS(63,a3)
        rp[(size_t)t * NN] = (a0 + a1) + (a2 + a3);
    }
}

// ---------- reduce partials over nc, mix, @Dy, relu (round-3 exact) ----------
__global__ __launch_bounds__(256) void k_y(const float* __restrict__ r_part,
                                           const float* __restrict__ Dy,
                                           const float* __restrict__ mixp,
                                           float* __restrict__ out) {
    int bb = blockIdx.x;
    int tg = bb & 15, b = bb >> 4;
    int tid = threadIdx.x;
    __shared__ float mixs[3][NN];
    float alpha = 1.f / (1.f + expf(-mixp[0]));

#pragma unroll
    for (int tt = 0; tt < 3; tt++) {
        int t = tg * 3 + tt;
        float spx = 0.f, spy = 0.f, spz = 0.f, spw = 0.f;
        float stx = 0.f, sty = 0.f, stz = 0.f, stw = 0.f;
#pragma unroll
        for (int nc = 0; nc < 16; nc++) {
            int bidp = (b * 16 + nc);
            int bidt = ((8 + b) * 16 + nc);
            float4 p = *reinterpret_cast<const float4*>(r_part + ((size_t)bidp * TT + t) * NN + tid * 4);
            float4 q = *reinterpret_cast<const float4*>(r_part + ((size_t)bidt * TT + t) * NN + tid * 4);
            spx += p.x; spy += p.y; spz += p.z; spw += p.w;
            stx += q.x; sty += q.y; stz += q.z; stw += q.w;
        }
        float4 m4;
        m4.x = alpha * spx + (1.f - alpha) * stx;
        m4.y = alpha * spy + (1.f - alpha) * sty;
        m4.z = alpha * spz + (1.f - alpha) * stz;
        m4.w = alpha * spw + (1.f - alpha) * stw;
        *reinterpret_cast<float4*>(&mixs[tt][tid * 4]) = m4;
    }
    __syncthreads();

    float acc[3][2];
#pragma unroll
    for (int tt = 0; tt < 3; tt++) { acc[tt][0] = 0.f; acc[tt][1] = 0.f; }

    for (int m = 0; m < NN; m += 4) {
        float w[3][4];
#pragma unroll
        for (int tt = 0; tt < 3; tt++) {
            float4 v = *reinterpret_cast<const float4*>(&mixs[tt][m]);
            w[tt][0] = v.x; w[tt][1] = v.y; w[tt][2] = v.z; w[tt][3] = v.w;
        }
#pragma unroll
        for (int j = 0; j < 4; j++) {
            float d0 = Dy[(size_t)(m + j) * DD + tid];
            float d1 = Dy[(size_t)(m + j) * DD + tid + 256];
#pragma unroll
            for (int tt = 0; tt < 3; tt++) {
                acc[tt][0] = fmaf(w[tt][j], d0, acc[tt][0]);
                acc[tt][1] = fmaf(w[tt][j], d1, acc[tt][1]);
            }
        }
    }
#pragma unroll
    for (int tt = 0; tt < 3; tt++) {
        int t = tg * 3 + tt;
        out[((size_t)b * TT + t) * DD + tid]       = fmaxf(acc[tt][0], 0.f);
        out[((size_t)b * TT + t) * DD + tid + 256] = fmaxf(acc[tt][1], 0.f);
    }
}

extern "C" void kernel_launch(void* const* d_in, const int* in_sizes, int n_in,
                              void* d_out, int out_size, void* d_ws, size_t ws_size,
                              hipStream_t stream) {
    const float* x    = (const float*)d_in[0];   // [8,48,512]
    const float* tg   = (const float*)d_in[1];   // [8,48,512]
    const float* E    = (const float*)d_in[2];   // [512,1024]
    const float* Dy   = (const float*)d_in[3];   // [1024,512]
    const float* mixp = (const float*)d_in[4];   // scalar
    float* out = (float*)d_out;                  // [8,48,512]

    float* ws = (float*)d_ws;
    float* z_x    = ws;                               // 384*1024
    float* z_t    = z_x + (size_t)384 * 1024;
    float* xn     = z_t + (size_t)384 * 1024;
    float* tn     = xn + (size_t)384 * 1024;
    float* r_part = tn + (size_t)384 * 1024;          // 256 chunks * 48 * 1024 floats

    k_gemm_z<<<384, 256, 0, stream>>>(x, tg, E, z_x, z_t);
    k_ln<<<384, 256, 0, stream>>>(z_x, z_t, xn, tn);
    k_sweep<<<1024, 256, 0, stream>>>(xn, tn, r_part);
    k_y<<<128, 256, 0, stream>>>(r_part, Dy, mixp, out);
}

// Round 8
// 190.970 us; speedup vs baseline: 1.4275x; 1.0138x over previous
//
#include <hip/hip_runtime.h>
#include <math.h>

#define BB 8
#define TT 48
#define DD 512
#define NN 1024

// ---------- z = [x ; tgt_next] @ E (round-6 exact) ----------
__global__ __launch_bounds__(256) void k_gemm_z(const float* __restrict__ x,
                                                const float* __restrict__ tg,
                                                const float* __restrict__ E,
                                                float* __restrict__ z_x,
                                                float* __restrict__ z_t) {
    int br = blockIdx.x;
    int tid = threadIdx.x;
    int col0 = tid * 4;

    const float* row[2];
#pragma unroll
    for (int i = 0; i < 2; i++) {
        int gr = br * 2 + i;
        if (gr < BB * TT) {
            row[i] = x + (size_t)gr * DD;
        } else {
            int bt = gr - BB * TT;
            int s = bt + 1;
            if (s > BB * TT - 1) s = BB * TT - 1;  // t=47 rows: garbage, masked by k_ln
            row[i] = tg + (size_t)s * DD;
        }
    }

    float4 acc0 = make_float4(0.f, 0.f, 0.f, 0.f);
    float4 acc1 = make_float4(0.f, 0.f, 0.f, 0.f);
    for (int d = 0; d < DD; d++) {
        float4 e = *reinterpret_cast<const float4*>(E + (size_t)d * NN + col0);
        float a0 = row[0][d];
        float a1 = row[1][d];
        acc0.x = fmaf(a0, e.x, acc0.x);
        acc0.y = fmaf(a0, e.y, acc0.y);
        acc0.z = fmaf(a0, e.z, acc0.z);
        acc0.w = fmaf(a0, e.w, acc0.w);
        acc1.x = fmaf(a1, e.x, acc1.x);
        acc1.y = fmaf(a1, e.y, acc1.y);
        acc1.z = fmaf(a1, e.z, acc1.z);
        acc1.w = fmaf(a1, e.w, acc1.w);
    }

#pragma unroll
    for (int i = 0; i < 2; i++) {
        int gr = br * 2 + i;
        float4 v = (i == 0) ? acc0 : acc1;
        if (gr < BB * TT)
            *reinterpret_cast<float4*>(z_x + (size_t)gr * NN + col0) = v;
        else
            *reinterpret_cast<float4*>(z_t + (size_t)(gr - BB * TT) * NN + col0) = v;
    }
}

// ---------- LN + relu (round-3 exact) ----------
__global__ __launch_bounds__(256) void k_ln(const float* __restrict__ z_x,
                                            const float* __restrict__ z_t,
                                            float* __restrict__ xn,
                                            float* __restrict__ tn) {
    int bt = blockIdx.x;
    int t = bt % TT;
    int tid = threadIdx.x;
    __shared__ float rs_[256], rq_[256];

    const float* src = z_x + (size_t)bt * NN;
    float v0 = src[tid], v1 = src[tid + 256], v2 = src[tid + 512], v3 = src[tid + 768];
    rs_[tid] = v0 + v1 + v2 + v3;
    rq_[tid] = v0 * v0 + v1 * v1 + v2 * v2 + v3 * v3;
    __syncthreads();
    for (int off = 128; off > 0; off >>= 1) {
        if (tid < off) { rs_[tid] += rs_[tid + off]; rq_[tid] += rq_[tid + off]; }
        __syncthreads();
    }
    float mu = rs_[0] * (1.f / NN);
    float var = rq_[0] * (1.f / NN) - mu * mu;
    float rstd = rsqrtf(var + 1e-5f);
    float* xrow = xn + (size_t)bt * NN;
    xrow[tid]       = fmaxf((v0 - mu) * rstd, 0.f);
    xrow[tid + 256] = fmaxf((v1 - mu) * rstd, 0.f);
    xrow[tid + 512] = fmaxf((v2 - mu) * rstd, 0.f);
    xrow[tid + 768] = fmaxf((v3 - mu) * rstd, 0.f);
    __syncthreads();

    float* trow = tn + (size_t)bt * NN;
    if (t < TT - 1) {
        const float* s2 = z_t + (size_t)bt * NN;
        float u0 = s2[tid], u1 = s2[tid + 256], u2 = s2[tid + 512], u3 = s2[tid + 768];
        rs_[tid] = u0 + u1 + u2 + u3;
        rq_[tid] = u0 * u0 + u1 * u1 + u2 * u2 + u3 * u3;
        __syncthreads();
        for (int off = 128; off > 0; off >>= 1) {
            if (tid < off) { rs_[tid] += rs_[tid + off]; rq_[tid] += rq_[tid + off]; }
            __syncthreads();
        }
        float mu2 = rs_[0] * (1.f / NN);
        float var2 = rq_[0] * (1.f / NN) - mu2 * mu2;
        float r2 = rsqrtf(var2 + 1e-5f);
        trow[tid]       = fmaxf((u0 - mu2) * r2, 0.f);
        trow[tid + 256] = fmaxf((u1 - mu2) * r2, 0.f);
        trow[tid + 512] = fmaxf((u2 - mu2) * r2, 0.f);
        trow[tid + 768] = fmaxf((u3 - mu2) * r2, 0.f);
    } else {
        trow[tid] = 0.f; trow[tid + 256] = 0.f; trow[tid + 512] = 0.f; trow[tid + 768] = 0.f;
    }
}

// ---------- the recurrence: G in 64 NAMED registers, weights via s_load -> SGPR ----------
// 1024 blocks: bid = state<<9 | b<<6 | nc<<2 | ccg. Wave wid -> col chunk cc=ccg*4+wid.
// Branchless (wn==0 is a bit-exact no-op since xn,g >= 0). The 64 wave-uniform
// weights are fetched by 4x s_load_dwordx16 into SGPRs: zero VGPR cost, zero VALU
// cost, and each FMA takes the weight as its single SGPR operand.

typedef __attribute__((ext_vector_type(16))) float f16v;

#define GI(n) float g##n = (state == 0 && nc == cc && (n) == lane) ? 0.5f : 0.f;
#define REP64(X) X(0) X(1) X(2) X(3) X(4) X(5) X(6) X(7) X(8) X(9) X(10) X(11) X(12) X(13) \
    X(14) X(15) X(16) X(17) X(18) X(19) X(20) X(21) X(22) X(23) X(24) X(25) X(26) X(27) \
    X(28) X(29) X(30) X(31) X(32) X(33) X(34) X(35) X(36) X(37) X(38) X(39) X(40) X(41) \
    X(42) X(43) X(44) X(45) X(46) X(47) X(48) X(49) X(50) X(51) X(52) X(53) X(54) X(55) \
    X(56) X(57) X(58) X(59) X(60) X(61) X(62) X(63)

#define GS(W, I, n, A) { float wn = (W)[I]; A = fmaf(wn, g##n, A); g##n = fmaxf(g##n, wn * mh); }

__global__ __launch_bounds__(256, 2) void k_sweep(const float* __restrict__ xn,
                                                  const float* __restrict__ tn,
                                                  float* __restrict__ r_part) {
    int bid = blockIdx.x;
    int ccg = bid & 3, nc = (bid >> 2) & 15, b = (bid >> 6) & 7, state = bid >> 9;
    int tid = threadIdx.x;
    int lane = tid & 63;
    int wid = __builtin_amdgcn_readfirstlane(tid >> 6);
    int cc = ccg * 4 + wid;
    int n0 = nc * 64;
    int col = cc * 64 + lane;

    REP64(GI)

    const float* wb  = xn + (size_t)b * TT * NN + n0;              // wave-uniform rows
    const float* mvb = (state ? tn : xn) + (size_t)b * TT * NN + col;
    float* rp = r_part + ((size_t)((state * 8 + b) * 16 + nc) * TT) * NN + col;

#pragma unroll 1
    for (int t = 0; t < TT; t++) {
        const float* xrow = wb + (size_t)t * NN;
        f16v w0, w1, w2, w3;
        asm volatile("s_load_dwordx16 %0, %4, 0x0\n\t"
                     "s_load_dwordx16 %1, %4, 0x40\n\t"
                     "s_load_dwordx16 %2, %4, 0x80\n\t"
                     "s_load_dwordx16 %3, %4, 0xc0\n\t"
                     "s_waitcnt lgkmcnt(0)"
                     : "=s"(w0), "=s"(w1), "=s"(w2), "=s"(w3)
                     : "s"(xrow)
                     : "memory");
        float mv = mvb[(size_t)t * NN];
        float sc = (t < TT - 1) ? 0.5f : 0.0f;     // folds do_upd into the operand
        float mh = mv * sc;
        float a0 = 0.f, a1 = 0.f, a2 = 0.f, a3 = 0.f;
        GS(w0,0,0,a0)   GS(w0,1,1,a1)   GS(w0,2,2,a2)   GS(w0,3,3,a3)
        GS(w0,4,4,a0)   GS(w0,5,5,a1)   GS(w0,6,6,a2)   GS(w0,7,7,a3)
        GS(w0,8,8,a0)   GS(w0,9,9,a1)   GS(w0,10,10,a2) GS(w0,11,11,a3)
        GS(w0,12,12,a0) GS(w0,13,13,a1) GS(w0,14,14,a2) GS(w0,15,15,a3)
        GS(w1,0,16,a0)  GS(w1,1,17,a1)  GS(w1,2,18,a2)  GS(w1,3,19,a3)
        GS(w1,4,20,a0)  GS(w1,5,21,a1)  GS(w1,6,22,a2)  GS(w1,7,23,a3)
        GS(w1,8,24,a0)  GS(w1,9,25,a1)  GS(w1,10,26,a2) GS(w1,11,27,a3)
        GS(w1,12,28,a0) GS(w1,13,29,a1) GS(w1,14,30,a2) GS(w1,15,31,a3)
        GS(w2,0,32,a0)  GS(w2,1,33,a1)  GS(w2,2,34,a2)  GS(w2,3,35,a3)
        GS(w2,4,36,a0)  GS(w2,5,37,a1)  GS(w2,6,38,a2)  GS(w2,7,39,a3)
        GS(w2,8,40,a0)  GS(w2,9,41,a1)  GS(w2,10,42,a2) GS(w2,11,43,a3)
        GS(w2,12,44,a0) GS(w2,13,45,a1) GS(w2,14,46,a2) GS(w2,15,47,a3)
        GS(w3,0,48,a0)  GS(w3,1,49,a1)  GS(w3,2,50,a2)  GS(w3,3,51,a3)
        GS(w3,4,52,a0)  GS(w3,5,53,a1)  GS(w3,6,54,a2)  GS(w3,7,55,a3)
        GS(w3,8,56,a0)  GS(w3,9,57,a1)  GS(w3,10,58,a2) GS(w3,11,59,a3)
        GS(w3,12,60,a0) GS(w3,13,61,a1) GS(w3,14,62,a2) GS(w3,15,63,a3)
        rp[(size_t)t * NN] = (a0 + a1) + (a2 + a3);
    }
}

// ---------- reduce partials over nc, mix, @Dy, relu (round-3 exact) ----------
__global__ __launch_bounds__(256) void k_y(const float* __restrict__ r_part,
                                           const float* __restrict__ Dy,
                                           const float* __restrict__ mixp,
                                           float* __restrict__ out) {
    int bb = blockIdx.x;
    int tg = bb & 15, b = bb >> 4;
    int tid = threadIdx.x;
    __shared__ float mixs[3][NN];
    float alpha = 1.f / (1.f + expf(-mixp[0]));

#pragma unroll
    for (int tt = 0; tt < 3; tt++) {
        int t = tg * 3 + tt;
        float spx = 0.f, spy = 0.f, spz = 0.f, spw = 0.f;
        float stx = 0.f, sty = 0.f, stz = 0.f, stw = 0.f;
#pragma unroll
        for (int nc = 0; nc < 16; nc++) {
            int bidp = (b * 16 + nc);
            int bidt = ((8 + b) * 16 + nc);
            float4 p = *reinterpret_cast<const float4*>(r_part + ((size_t)bidp * TT + t) * NN + tid * 4);
            float4 q = *reinterpret_cast<const float4*>(r_part + ((size_t)bidt * TT + t) * NN + tid * 4);
            spx += p.x; spy += p.y; spz += p.z; spw += p.w;
            stx += q.x; sty += q.y; stz += q.z; stw += q.w;
        }
        float4 m4;
        m4.x = alpha * spx + (1.f - alpha) * stx;
        m4.y = alpha * spy + (1.f - alpha) * sty;
        m4.z = alpha * spz + (1.f - alpha) * stz;
        m4.w = alpha * spw + (1.f - alpha) * stw;
        *reinterpret_cast<float4*>(&mixs[tt][tid * 4]) = m4;
    }
    __syncthreads();

    float acc[3][2];
#pragma unroll
    for (int tt = 0; tt < 3; tt++) { acc[tt][0] = 0.f; acc[tt][1] = 0.f; }

    for (int m = 0; m < NN; m += 4) {
        float w[3][4];
#pragma unroll
        for (int tt = 0; tt < 3; tt++) {
            float4 v = *reinterpret_cast<const float4*>(&mixs[tt][m]);
            w[tt][0] = v.x; w[tt][1] = v.y; w[tt][2] = v.z; w[tt][3] = v.w;
        }
#pragma unroll
        for (int j = 0; j < 4; j++) {
            float d0 = Dy[(size_t)(m + j) * DD + tid];
            float d1 = Dy[(size_t)(m + j) * DD + tid + 256];
#pragma unroll
            for (int tt = 0; tt < 3; tt++) {
                acc[tt][0] = fmaf(w[tt][j], d0, acc[tt][0]);
                acc[tt][1] = fmaf(w[tt][j], d1, acc[tt][1]);
            }
        }
    }
#pragma unroll
    for (int tt = 0; tt < 3; tt++) {
        int t = tg * 3 + tt;
        out[((size_t)b * TT + t) * DD + tid]       = fmaxf(acc[tt][0], 0.f);
        out[((size_t)b * TT + t) * DD + tid + 256] = fmaxf(acc[tt][1], 0.f);
    }
}

extern "C" void kernel_launch(void* const* d_in, const int* in_sizes, int n_in,
                              void* d_out, int out_size, void* d_ws, size_t ws_size,
                              hipStream_t stream) {
    const float* x    = (const float*)d_in[0];   // [8,48,512]
    const float* tg   = (const float*)d_in[1];   // [8,48,512]
    const float* E    = (const float*)d_in[2];   // [512,1024]
    const float* Dy   = (const float*)d_in[3];   // [1024,512]
    const float* mixp = (const float*)d_in[4];   // scalar
    float* out = (float*)d_out;                  // [8,48,512]

    float* ws = (float*)d_ws;
    float* z_x    = ws;                               // 384*1024
    float* z_t    = z_x + (size_t)384 * 1024;
    float* xn     = z_t + (size_t)384 * 1024;
    float* tn     = xn + (size_t)384 * 1024;
    float* r_part = tn + (size_t)384 * 1024;          // 256 chunks * 48 * 1024 floats

    k_gemm_z<<<384, 256, 0, stream>>>(x, tg, E, z_x, z_t);
    k_ln<<<384, 256, 0, stream>>>(z_x, z_t, xn, tn);
    k_sweep<<<1024, 256, 0, stream>>>(xn, tn, r_part);
    k_y<<<128, 256, 0, stream>>>(r_part, Dy, mixp, out);
}